// Round 2
// baseline (524.837 us; speedup 1.0000x reference)
//
#include <hip/hip_runtime.h>
#include <hip/hip_bf16.h>
#include <stdint.h>

// WindowAttention: B=8192 windows, N=64 tokens, C=128, H=4 heads, hd=32.
// One block per window, 4 waves, wave = head. bf16 MFMA 16x16x32 throughout.

typedef __bf16 bf16x8 __attribute__((ext_vector_type(8)));
typedef float floatx4 __attribute__((ext_vector_type(4)));

#define MFMA16(A, B, C) __builtin_amdgcn_mfma_f32_16x16x32_bf16((A), (B), (C), 0, 0, 0)

__device__ __forceinline__ unsigned short f2bf(float f) {
    union { float f; uint32_t u; } v; v.f = f;
    uint32_t r = v.u + 0x7FFFu + ((v.u >> 16) & 1u);   // RNE; inputs are finite
    return (unsigned short)(r >> 16);
}
__device__ __forceinline__ uint32_t pk2(float a, float b) {
    return (uint32_t)f2bf(a) | ((uint32_t)f2bf(b) << 16);
}
__device__ __forceinline__ bf16x8 lds_frag(const char* p) {
    return *(const bf16x8*)p;
}

// ---------------- pre-kernel: pack weights to bf16 fragment order + gather bias ----
// wq_p entry (rb,kk,lane): 8 bf16 = W[rb*16 + (lane&15)][kk*32 + (lane>>4)*8 + j]
// (identical k-slot mapping is used for every LDS fragment read in the main kernel,
//  so any intra-fragment k permutation cancels: reductions are permutation-invariant)
__global__ void prep(const float* __restrict__ wqkv, const float* __restrict__ wproj,
                     const float* __restrict__ btab, const int* __restrict__ rpi,
                     unsigned short* __restrict__ wq_p, unsigned short* __restrict__ wp_p,
                     float* __restrict__ biasP) {
    int tid = blockIdx.x * blockDim.x + threadIdx.x;
    if (tid < 6144) {   // 24 rowblks * 4 kk * 64 lanes
        int lane = tid & 63, kk = (tid >> 6) & 3, rb = tid >> 8;
        int row = rb * 16 + (lane & 15);
        int k0 = kk * 32 + (lane >> 4) * 8;
        for (int j = 0; j < 8; ++j) wq_p[tid * 8 + j] = f2bf(wqkv[row * 128 + k0 + j]);
    }
    if (tid < 2048) {   // 8 rowblks * 4 kk * 64 lanes
        int lane = tid & 63, kk = (tid >> 6) & 3, rb = tid >> 8;
        int row = rb * 16 + (lane & 15);
        int k0 = kk * 32 + (lane >> 4) * 8;
        for (int j = 0; j < 8; ++j) wp_p[tid * 8 + j] = f2bf(wproj[row * 128 + k0 + j]);
    }
    if (tid < 16384) {  // biasP[h][q][k] = btab[rpi[q][k]][h]
        int k = tid & 63, q = (tid >> 6) & 63, h = tid >> 12;
        biasP[tid] = btab[rpi[q * 64 + k] * 4 + h];
    }
}

// ---------------- main kernel ----------------
// LDS (48KB): region A [0,16384): xb[64][128]bf16 -> Vt[4 heads][32][64] -> outL[64][128]
//             region B [16384,49152): per head 8KB: Q[64][32]|K[64][32] -> Pq[64][64]
// All row-major tiles XOR-swizzled; all LDS writes are 8B packed, all frag reads 16B.
__global__ __launch_bounds__(256, 3) void winattn(
    const float* __restrict__ x, const unsigned short* __restrict__ wq_p,
    const unsigned short* __restrict__ wp_p, const float* __restrict__ biasP,
    const float* __restrict__ bproj, float* __restrict__ y) {

    __shared__ __align__(16) char sm[49152];
    const int tid = threadIdx.x;
    const int lane = tid & 63;
    const int wid = tid >> 6;           // head
    const int l15 = lane & 15;
    const int g = lane >> 4;
    const int win = blockIdx.x;
    const floatx4 z4 = {0.f, 0.f, 0.f, 0.f};

    // ---- stage 0: x -> xb bf16 (rows 256B, swizzle byte^((row&7)<<4)) ----
    {
        const float* xw = x + (size_t)win * 8192;
        for (int i = 0; i < 8; ++i) {
            int fi = i * 1024 + tid * 4;
            float4 v = *(const float4*)(xw + fi);
            int row = fi >> 7, col = fi & 127;
            int off = (col * 2) ^ ((row & 7) << 4);
            uint2 p; p.x = pk2(v.x, v.y); p.y = pk2(v.z, v.w);
            *(uint2*)(&sm[row * 256 + off]) = p;
        }
    }
    __syncthreads();

    const bf16x8* wq8 = (const bf16x8*)wq_p;
    const int qbase = 16384 + wid * 8192;
    const int kbase = qbase + 4096;

    // ---- stage 1: q,k = W @ x^T (output channel-major) ----
    floatx4 accA[4][4];
    for (int a = 0; a < 4; ++a) for (int b = 0; b < 4; ++b) accA[a][b] = z4;
    for (int kk = 0; kk < 4; ++kk) {
        bf16x8 bfr[4];
        for (int nt = 0; nt < 4; ++nt) {
            int row = l15 + 16 * nt;
            int off = (kk * 64 + g * 16) ^ ((row & 7) << 4);
            bfr[nt] = lds_frag(&sm[row * 256 + off]);
        }
        for (int mi = 0; mi < 4; ++mi) {
            int rb = (mi < 2) ? (2 * wid + mi) : (8 + 2 * wid + mi - 2);
            bf16x8 afr = wq8[(rb * 4 + kk) * 64 + lane];
            for (int nt = 0; nt < 4; ++nt)
                accA[mi][nt] = MFMA16(afr, bfr[nt], accA[mi][nt]);
        }
    }
    // write Q (pre-scaled by 1/sqrt(hd)) and K: rows 64B, swizzle ((tok&3)<<4).
    // Same-wave producer/consumer only -> no barrier.
    const float qscale = 0.17677669529663689f;
    for (int mi = 0; mi < 2; ++mi) for (int nt = 0; nt < 4; ++nt) {
        int tok = l15 + 16 * nt;
        int off = (mi * 32 + g * 8) ^ ((tok & 3) << 4);
        floatx4 aq = accA[mi][nt];
        uint2 pq; pq.x = pk2(aq[0] * qscale, aq[1] * qscale); pq.y = pk2(aq[2] * qscale, aq[3] * qscale);
        *(uint2*)(&sm[qbase + tok * 64 + off]) = pq;
        floatx4 ak = accA[mi + 2][nt];
        uint2 pkk; pkk.x = pk2(ak[0], ak[1]); pkk.y = pk2(ak[2], ak[3]);
        *(uint2*)(&sm[kbase + tok * 64 + off]) = pkk;
    }

    // ---- stage 1b: v = x @ W^T (token-major output -> packed Vt writes) ----
    floatx4 accV[4][2];
    for (int a = 0; a < 4; ++a) for (int b = 0; b < 2; ++b) accV[a][b] = z4;
    for (int kk = 0; kk < 4; ++kk) {
        bf16x8 afr[4];
        for (int mt = 0; mt < 4; ++mt) {
            int row = l15 + 16 * mt;
            int off = (kk * 64 + g * 16) ^ ((row & 7) << 4);
            afr[mt] = lds_frag(&sm[row * 256 + off]);
        }
        for (int nt = 0; nt < 2; ++nt) {
            bf16x8 bfr = wq8[((16 + 2 * wid + nt) * 4 + kk) * 64 + lane];
            for (int mt = 0; mt < 4; ++mt)
                accV[mt][nt] = MFMA16(afr[mt], bfr, accV[mt][nt]);
        }
    }
    __syncthreads();            // barrier1: all xb reads done (Vt aliases xb)
    // Vt[head][e][tok]: rows 128B, swizzle ((e&7)<<4)
    for (int mt = 0; mt < 4; ++mt) for (int nt = 0; nt < 2; ++nt) {
        int e = l15 + 16 * nt;
        int off = ((mt * 16 + g * 4) * 2) ^ ((e & 7) << 4);
        floatx4 av = accV[mt][nt];
        uint2 pv; pv.x = pk2(av[0], av[1]); pv.y = pk2(av[2], av[3]);
        *(uint2*)(&sm[wid * 4096 + e * 128 + off]) = pv;
    }

    // ---- stage 2: S^T = K @ Q^T  (K=32 -> single MFMA per tile) ----
    floatx4 accS[4][4];
    for (int a = 0; a < 4; ++a) for (int b = 0; b < 4; ++b) accS[a][b] = z4;
    {
        bf16x8 kfr[4], qfr[4];
        for (int t = 0; t < 4; ++t) {
            int row = l15 + 16 * t;
            int off = (g * 16) ^ ((row & 3) << 4);
            kfr[t] = lds_frag(&sm[kbase + row * 64 + off]);
            qfr[t] = lds_frag(&sm[qbase + row * 64 + off]);
        }
        for (int mt = 0; mt < 4; ++mt)
            for (int nt = 0; nt < 4; ++nt)
                accS[mt][nt] = MFMA16(kfr[mt], qfr[nt], accS[mt][nt]);
    }

    // ---- softmax over k (lane holds S[q=l15+16nt][k=16mt+4g+r]) ----
    const float* bp = biasP + wid * 4096;
    float rs[4];
    floatx4 P[4][4];
    for (int nt = 0; nt < 4; ++nt) {
        int q = l15 + 16 * nt;
        float mx = -3.0e38f;
        for (int mt = 0; mt < 4; ++mt) {
            float4 b4 = *(const float4*)(bp + q * 64 + mt * 16 + g * 4);
            floatx4 lg = accS[mt][nt];
            lg[0] += b4.x; lg[1] += b4.y; lg[2] += b4.z; lg[3] += b4.w;
            P[mt][nt] = lg;
            mx = fmaxf(mx, fmaxf(fmaxf(lg[0], lg[1]), fmaxf(lg[2], lg[3])));
        }
        mx = fmaxf(mx, __shfl_xor(mx, 16));
        mx = fmaxf(mx, __shfl_xor(mx, 32));
        float sum = 0.f;
        for (int mt = 0; mt < 4; ++mt) {
            floatx4 e = P[mt][nt];
            e[0] = __expf(e[0] - mx); e[1] = __expf(e[1] - mx);
            e[2] = __expf(e[2] - mx); e[3] = __expf(e[3] - mx);
            P[mt][nt] = e;
            sum += e[0] + e[1] + e[2] + e[3];
        }
        sum += __shfl_xor(sum, 16);
        sum += __shfl_xor(sum, 32);
        rs[nt] = 1.0f / sum;    // normalization deferred to PV epilogue
    }
    __syncthreads();            // safety: S^T frag reads done before Pq overwrites Q|K
    const int pqbase = 16384 + wid * 8192;      // Pq[64][64] rows 128B, swizzle ((q&7)<<4)
    for (int nt = 0; nt < 4; ++nt) {
        int q = l15 + 16 * nt;
        for (int mt = 0; mt < 4; ++mt) {
            int off = ((mt * 16 + g * 4) * 2) ^ ((q & 7) << 4);
            floatx4 e = P[mt][nt];
            uint2 pp; pp.x = pk2(e[0], e[1]); pp.y = pk2(e[2], e[3]);
            *(uint2*)(&sm[pqbase + q * 128 + off]) = pp;
        }
    }

    // ---- stage 3: out^T = Vt @ Pq^T ----
    floatx4 accO[2][4];
    for (int a = 0; a < 2; ++a) for (int b = 0; b < 4; ++b) accO[a][b] = z4;
    for (int ks = 0; ks < 2; ++ks) {
        bf16x8 afr[2], bfr[4];
        for (int mt = 0; mt < 2; ++mt) {
            int row = l15 + 16 * mt;
            int off = (ks * 64 + g * 16) ^ ((row & 7) << 4);
            afr[mt] = lds_frag(&sm[wid * 4096 + row * 128 + off]);
        }
        for (int nt = 0; nt < 4; ++nt) {
            int row = l15 + 16 * nt;
            int off = (ks * 64 + g * 16) ^ ((row & 7) << 4);
            bfr[nt] = lds_frag(&sm[pqbase + row * 128 + off]);
        }
        for (int mt = 0; mt < 2; ++mt)
            for (int nt = 0; nt < 4; ++nt)
                accO[mt][nt] = MFMA16(afr[mt], bfr[nt], accO[mt][nt]);
    }
    __syncthreads();            // barrier3: Vt reads done (outL aliases region A)
    // outL[tok][c] rows 256B, same swizzle as xb; apply deferred 1/sum here
    for (int mt = 0; mt < 2; ++mt) for (int nt = 0; nt < 4; ++nt) {
        int q = l15 + 16 * nt;
        int cb = wid * 32 + mt * 16 + g * 4;
        int off = (cb * 2) ^ ((q & 7) << 4);
        floatx4 o = accO[mt][nt];
        float r = rs[nt];
        uint2 po; po.x = pk2(o[0] * r, o[1] * r); po.y = pk2(o[2] * r, o[3] * r);
        *(uint2*)(&sm[q * 256 + off]) = po;
    }
    __syncthreads();            // barrier4: outL complete

    // ---- stage 4: y^T = Wp @ out^T ----
    floatx4 accY[2][4];
    for (int a = 0; a < 2; ++a) for (int b = 0; b < 4; ++b) accY[a][b] = z4;
    const bf16x8* wp8 = (const bf16x8*)wp_p;
    for (int kk = 0; kk < 4; ++kk) {
        bf16x8 bfr[4];
        for (int nt = 0; nt < 4; ++nt) {
            int row = l15 + 16 * nt;
            int off = (kk * 64 + g * 16) ^ ((row & 7) << 4);
            bfr[nt] = lds_frag(&sm[row * 256 + off]);
        }
        for (int mt = 0; mt < 2; ++mt) {
            bf16x8 afr = wp8[((2 * wid + mt) * 4 + kk) * 64 + lane];
            for (int nt = 0; nt < 4; ++nt)
                accY[mt][nt] = MFMA16(afr, bfr[nt], accY[mt][nt]);
        }
    }
    // epilogue: +b_proj, f32 stores (4-lane groups form 64B contiguous segments)
    float* yw = y + (size_t)win * 8192;
    for (int mt = 0; mt < 2; ++mt) {
        int cb = wid * 32 + mt * 16 + g * 4;
        float4 b4 = *(const float4*)(bproj + cb);
        for (int nt = 0; nt < 4; ++nt) {
            int tok = l15 + 16 * nt;
            float4 o;
            o.x = accY[mt][nt][0] + b4.x;
            o.y = accY[mt][nt][1] + b4.y;
            o.z = accY[mt][nt][2] + b4.z;
            o.w = accY[mt][nt][3] + b4.w;
            *(float4*)(yw + tok * 128 + cb) = o;
        }
    }
}

extern "C" void kernel_launch(void* const* d_in, const int* in_sizes, int n_in,
                              void* d_out, int out_size, void* d_ws, size_t ws_size,
                              hipStream_t stream) {
    const float* x     = (const float*)d_in[0];
    const float* wqkv  = (const float*)d_in[1];
    const float* wproj = (const float*)d_in[2];
    const float* bproj = (const float*)d_in[3];
    const float* btab  = (const float*)d_in[4];
    const int*   rpi   = (const int*)d_in[5];

    unsigned short* wq_p = (unsigned short*)d_ws;                       // 98304 B
    unsigned short* wp_p = (unsigned short*)((char*)d_ws + 98304);      // 32768 B
    float* biasP         = (float*)((char*)d_ws + 131072);              // 65536 B

    int nwin = in_sizes[0] >> 13;   // elements per window = 64*128
    prep<<<64, 256, 0, stream>>>(wqkv, wproj, btab, rpi, wq_p, wp_p, biasP);
    winattn<<<nwin, 256, 0, stream>>>(x, wq_p, wp_p, biasP, bproj, (float*)d_out);
}